// Round 10
// baseline (752.878 us; speedup 1.0000x reference)
//
#include <hip/hip_runtime.h>

// Problem constants
#define BATCH 16384
#define DIM   256
#define KC    3000
#define KCPAD 3072
#define NBLK  256   // sinkp row-blocks per matrix (64 rows each)

typedef __bf16   bf16x4  __attribute__((ext_vector_type(4)));
typedef __bf16   bf16x8  __attribute__((ext_vector_type(8)));
typedef float    floatx4 __attribute__((ext_vector_type(4)));
typedef _Float16 half8   __attribute__((ext_vector_type(8)));

// async global->LDS, 16B per lane; LDS dest is wave-uniform base + lane*16
#define GLD16(gptr, lptr)                                                              \
  __builtin_amdgcn_global_load_lds((const __attribute__((address_space(1))) void*)(gptr), \
                                   (__attribute__((address_space(3))) void*)(lptr), 16, 0, 0)

// Full wave64 sum via DPP (VALU pipe, no ds_bpermute). Result valid in lane 63.
__device__ __forceinline__ float dpp_red_sum(float x) {
  int xi;
  xi = __builtin_amdgcn_update_dpp(0, __float_as_int(x), 0x111, 0xf, 0xf, true);
  x += __int_as_float(xi);
  xi = __builtin_amdgcn_update_dpp(0, __float_as_int(x), 0x112, 0xf, 0xf, true);
  x += __int_as_float(xi);
  xi = __builtin_amdgcn_update_dpp(0, __float_as_int(x), 0x114, 0xf, 0xf, true);
  x += __int_as_float(xi);
  xi = __builtin_amdgcn_update_dpp(0, __float_as_int(x), 0x118, 0xf, 0xf, true);
  x += __int_as_float(xi);
  xi = __builtin_amdgcn_update_dpp(0, __float_as_int(x), 0x142, 0xa, 0xf, false);
  x += __int_as_float(xi);
  xi = __builtin_amdgcn_update_dpp(0, __float_as_int(x), 0x143, 0xc, 0xf, false);
  x += __int_as_float(xi);
  return x;  // lane 63 = sum of all 64 lanes
}

// ---------------- normalize: one wave per row, float4 in, bf16x4 out ----------------
__global__ __launch_bounds__(256) void normalize_all(const float* __restrict__ q,
                                                     const float* __restrict__ k,
                                                     const float* __restrict__ c,
                                                     __bf16* __restrict__ nq,
                                                     __bf16* __restrict__ nk,
                                                     __bf16* __restrict__ nc) {
  const int wid = threadIdx.x >> 6;
  const int lane = threadIdx.x & 63;
  int row = blockIdx.x * 4 + wid;   // 0 .. 35839
  const float* src;
  __bf16* dst;
  int srow;
  bool live = true;
  if (row < BATCH) {
    src = q; dst = nq; srow = row;
  } else if (row < 2 * BATCH) {
    src = k; dst = nk; srow = row - BATCH;
  } else {
    src = c; dst = nc; srow = row - 2 * BATCH; live = srow < KC;
  }
  float4 v = make_float4(0.f, 0.f, 0.f, 0.f);
  if (live) v = *reinterpret_cast<const float4*>(&src[(size_t)srow * DIM + lane * 4]);
  float ss = v.x * v.x + v.y * v.y + v.z * v.z + v.w * v.w;
  ss = dpp_red_sum(ss);
  ss = __shfl(ss, 63, 64);
  float inv = 1.f / fmaxf(sqrtf(ss), 1e-12f);
  bf16x4 o;
  o[0] = (__bf16)(v.x * inv); o[1] = (__bf16)(v.y * inv);
  o[2] = (__bf16)(v.z * inv); o[3] = (__bf16)(v.w * inv);
  *reinterpret_cast<bf16x4*>(&dst[(size_t)srow * DIM + lane * 4]) = o;  // pad rows get 0
}

// ---------------- GEMM (async LDS staging, XOR-swizzled) + fused colsum0 ----------------
// LDS pos p=r*4+cc holds global 16B chunk (r, cc ^ swz(r)), swz(r)=(r&3)^((r>>2)&3).
// Reader for (row, quarter q) uses pos row*4 + (q^swz(row)) -> 2-way max bank aliasing.
__global__ __launch_bounds__(256) void gemm_bf16(const __bf16* __restrict__ A,
                                                 const __bf16* __restrict__ Bm,
                                                 _Float16* __restrict__ S,
                                                 float* __restrict__ csum0) {
  __shared__ __align__(16) __bf16 As[128 * 32];
  __shared__ __align__(16) __bf16 Bs[128 * 32];
  const int tid = threadIdx.x;
  const int bm = blockIdx.x * 128;
  const int bn = blockIdx.y * 128;
  const int wid = tid >> 6;
  const int lane = tid & 63;
  const int wm = (wid >> 1) * 64;
  const int wn = (wid & 1) * 64;
  const int frow = lane & 15;
  const int fq = lane >> 4;   // 16B-chunk quarter

  // precompute swizzled staging source offsets (constant across kt)
  int src_off[2];
#pragma unroll
  for (int c = 0; c < 2; ++c) {
    int idx = tid + c * 256;
    int r = idx >> 2;
    int cc = idx & 3;
    int swz = (r & 3) ^ ((r >> 2) & 3);
    src_off[c] = r * DIM + ((cc ^ swz) << 3);
  }
  // precompute swizzled fragment read addresses (constant across kt)
  int a_pos[4], b_pos[4];
#pragma unroll
  for (int i = 0; i < 4; ++i) {
    int rowA = wm + i * 16 + frow;
    int rowB = wn + i * 16 + frow;
    a_pos[i] = rowA * 32 + ((fq ^ ((rowA & 3) ^ ((rowA >> 2) & 3))) << 3);
    b_pos[i] = rowB * 32 + ((fq ^ ((rowB & 3) ^ ((rowB >> 2) & 3))) << 3);
  }

  floatx4 acc[4][4] = {};

  for (int kt = 0; kt < DIM; kt += 32) {
    __syncthreads();
#pragma unroll
    for (int c = 0; c < 2; ++c) {
      int idx = tid + c * 256;
      GLD16(A + (size_t)bm * DIM + kt + src_off[c], &As[idx * 8]);
      GLD16(Bm + (size_t)bn * DIM + kt + src_off[c], &Bs[idx * 8]);
    }
    __syncthreads();
    bf16x8 af[4], bfr[4];
#pragma unroll
    for (int i = 0; i < 4; ++i) af[i] = *reinterpret_cast<const bf16x8*>(&As[a_pos[i]]);
#pragma unroll
    for (int j = 0; j < 4; ++j) bfr[j] = *reinterpret_cast<const bf16x8*>(&Bs[b_pos[j]]);
#pragma unroll
    for (int i = 0; i < 4; ++i)
#pragma unroll
      for (int j = 0; j < 4; ++j)
        acc[i][j] = __builtin_amdgcn_mfma_f32_16x16x32_bf16(af[i], bfr[j], acc[i][j], 0, 0, 0);
  }

  const int rgrp = (lane >> 4) * 4;   // C/D: row = (lane>>4)*4 + reg, col = lane&15
  const int cl = lane & 15;
#pragma unroll
  for (int j = 0; j < 4; ++j) {
    int colb = bn + wn + j * 16 + cl;
    bool valid = colb < KC;
    float csumj = 0.f;
#pragma unroll
    for (int i = 0; i < 4; ++i) {
#pragma unroll
      for (int r = 0; r < 4; ++r) {
        int rowb = bm + wm + i * 16 + rgrp + r;
        float sv = acc[i][j][r];
        S[(size_t)rowb * KCPAD + colb] = (_Float16)(valid ? sv : -3000.0f);
        csumj += __expf(20.f * sv);
      }
    }
    csumj = valid ? csumj : 0.f;
    csumj += __shfl_xor(csumj, 16, 64);
    csumj += __shfl_xor(csumj, 32, 64);
    if (lane < 16 && valid) atomicAdd(&csum0[colb], csumj);
  }
}

// ---------------- column reduce (K and Q): partials -> u = 1/(K*sum), w = u*log(u) ----
__global__ __launch_bounds__(256) void reduB(const float* __restrict__ partK,
                                             const float* __restrict__ partQ, int nparts,
                                             float* __restrict__ uK, float* __restrict__ wK,
                                             float* __restrict__ uQ, float* __restrict__ wQ) {
  int b = blockIdx.x;  // 0..23
  const float* parts;
  float *u, *w;
  if (b < 12) { parts = partK; u = uK; w = wK; }
  else        { parts = partQ; u = uQ; w = wQ; b -= 12; }
  int col = b * 256 + threadIdx.x;
  float s;
  if (nparts == 1) {
    s = parts[col];
  } else {
    float a0 = 0.f, a1 = 0.f, a2 = 0.f, a3 = 0.f;
    for (int i = 0; i < nparts; i += 4) {
      a0 += parts[(size_t)(i + 0) * KCPAD + col];
      a1 += parts[(size_t)(i + 1) * KCPAD + col];
      a2 += parts[(size_t)(i + 2) * KCPAD + col];
      a3 += parts[(size_t)(i + 3) * KCPAD + col];
    }
    s = (a0 + a1) + (a2 + a3);
  }
  if (col >= KC) { u[col] = 0.f; w[col] = 0.f; return; }
  float uu = 1.f / (3000.f * s);
  u[col] = uu;
  w[col] = uu * logf(uu);
}

// ---------------- fused sinkhorn pass, single-buffer + in-place prefetch ----------------
// blocks 0..255 -> Sk rows, 256..511 -> Sq rows; 64 rows/block (4 chunks of 16).
// Per row: tot = sum_k exp(20s)*u[k]; v = 1/(B*tot); part[rblk][k] += exp(20s)*v.
// Phase B overwrites hv[r] with the NEXT chunk's row r right after its last read:
// next-chunk loads drain behind phase-B compute with zero extra registers.
__global__ __launch_bounds__(384, 2) void sinkp2(const _Float16* __restrict__ Sk,
                                                 const _Float16* __restrict__ Sq,
                                                 const float* __restrict__ uK,
                                                 const float* __restrict__ uQ,
                                                 float* __restrict__ partK,
                                                 float* __restrict__ partQ) {
  __shared__ float wred[16][6];
  __shared__ float vsh[16];
  const int t = threadIdx.x;
  const int w = t >> 6;
  const int lane = t & 63;
  const int col0 = t * 8;

  const _Float16* S;
  const float* uin;
  float* part;
  int rblk = blockIdx.x;
  if (rblk < NBLK) { S = Sk; uin = uK; part = partK; }
  else             { S = Sq; uin = uQ; part = partQ; rblk -= NBLK; }

  float u[8];
  {
    float4 c0 = *reinterpret_cast<const float4*>(&uin[col0]);
    float4 c1 = *reinterpret_cast<const float4*>(&uin[col0 + 4]);
    u[0] = c0.x; u[1] = c0.y; u[2] = c0.z; u[3] = c0.w;
    u[4] = c1.x; u[5] = c1.y; u[6] = c1.z; u[7] = c1.w;
  }

  const int r0 = rblk * 64;
  float creg[8] = {0.f, 0.f, 0.f, 0.f, 0.f, 0.f, 0.f, 0.f};

  half8 hv[16];
#pragma unroll
  for (int r = 0; r < 16; ++r)
    hv[r] = *reinterpret_cast<const half8*>(&S[(size_t)(r0 + r) * KCPAD + col0]);

#pragma unroll
  for (int ch = 0; ch < 4; ++ch) {
    float d[16];
#pragma unroll
    for (int r = 0; r < 16; ++r) {
      float dot = 0.f;
#pragma unroll
      for (int j = 0; j < 8; ++j) dot += __expf(20.f * (float)hv[r][j]) * u[j];
      d[r] = dot;
    }
    // 16 independent DPP reduction chains (VALU pipe)
#pragma unroll
    for (int r = 0; r < 16; ++r) d[r] = dpp_red_sum(d[r]);
    if (lane == 63) {
#pragma unroll
      for (int r = 0; r < 16; ++r) wred[r][w] = d[r];
    }
    __syncthreads();
    if (t < 16) {
      float tot = wred[t][0] + wred[t][1] + wred[t][2] + wred[t][3] + wred[t][4] + wred[t][5];
      vsh[t] = 1.f / (16384.f * tot);
    }
    __syncthreads();
    // phase B: accumulate col partials, then overwrite hv[r] with next chunk's row r
    const int rbn = r0 + (ch + 1) * 16;
#pragma unroll
    for (int r = 0; r < 16; ++r) {
      float v = vsh[r];
#pragma unroll
      for (int j = 0; j < 8; ++j) creg[j] += __expf(20.f * (float)hv[r][j]) * v;
      if (ch < 3)
        hv[r] = *reinterpret_cast<const half8*>(&S[(size_t)(rbn + r) * KCPAD + col0]);
    }
    // no 3rd barrier: next wred write races only against vsh reads (different arrays),
    // and the next B1 orders wred-write vs vsh-recompute.
  }

  float4* pp = reinterpret_cast<float4*>(&part[(size_t)rblk * KCPAD + col0]);
  pp[0] = make_float4(creg[0], creg[1], creg[2], creg[3]);
  pp[1] = make_float4(creg[4], creg[5], creg[6], creg[7]);
}

// ---------------- fused final-iteration + KL (both losses) ----------------
// 2-row chunks with explicit next-pair prefetch; 12 interleaved DPP chains.
__global__ __launch_bounds__(384, 2) void kl_kernel(
    const _Float16* __restrict__ Sk, const _Float16* __restrict__ Sq,
    const float* __restrict__ uK, const float* __restrict__ wK,
    const float* __restrict__ uQ, const float* __restrict__ wQ,
    float* __restrict__ accOut) {
  __shared__ float wred[32][6][6];  // [row][wave][quantity]
  const int t = threadIdx.x;
  const int w = t >> 6;
  const int lane = t & 63;
  const int col0 = t * 8;

  float uk[8], wk[8], uq[8], wq[8];
  {
    float4 a0 = *reinterpret_cast<const float4*>(&uK[col0]);
    float4 a1 = *reinterpret_cast<const float4*>(&uK[col0 + 4]);
    float4 b0 = *reinterpret_cast<const float4*>(&wK[col0]);
    float4 b1 = *reinterpret_cast<const float4*>(&wK[col0 + 4]);
    float4 c0 = *reinterpret_cast<const float4*>(&uQ[col0]);
    float4 c1 = *reinterpret_cast<const float4*>(&uQ[col0 + 4]);
    float4 e0 = *reinterpret_cast<const float4*>(&wQ[col0]);
    float4 e1 = *reinterpret_cast<const float4*>(&wQ[col0 + 4]);
    uk[0]=a0.x;uk[1]=a0.y;uk[2]=a0.z;uk[3]=a0.w;uk[4]=a1.x;uk[5]=a1.y;uk[6]=a1.z;uk[7]=a1.w;
    wk[0]=b0.x;wk[1]=b0.y;wk[2]=b0.z;wk[3]=b0.w;wk[4]=b1.x;wk[5]=b1.y;wk[6]=b1.z;wk[7]=b1.w;
    uq[0]=c0.x;uq[1]=c0.y;uq[2]=c0.z;uq[3]=c0.w;uq[4]=c1.x;uq[5]=c1.y;uq[6]=c1.z;uq[7]=c1.w;
    wq[0]=e0.x;wq[1]=e0.y;wq[2]=e0.z;wq[3]=e0.w;wq[4]=e1.x;wq[5]=e1.y;wq[6]=e1.z;wq[7]=e1.w;
  }

  const int r0 = blockIdx.x * 32;
  size_t base0 = (size_t)r0 * KCPAD + col0;
  half8 a0 = *reinterpret_cast<const half8*>(&Sk[base0]);
  half8 b0 = *reinterpret_cast<const half8*>(&Sq[base0]);
  half8 a1 = *reinterpret_cast<const half8*>(&Sk[base0 + KCPAD]);
  half8 b1 = *reinterpret_cast<const half8*>(&Sq[base0 + KCPAD]);

#pragma unroll
  for (int r = 0; r < 32; r += 2) {
    // prefetch next pair (wraps to row 0 on last iter: redundant but harmless)
    const int rn = (r + 2 < 32) ? r + 2 : 0;
    size_t nb = (size_t)(r0 + rn) * KCPAD + col0;
    half8 na0 = *reinterpret_cast<const half8*>(&Sk[nb]);
    half8 nb0 = *reinterpret_cast<const half8*>(&Sq[nb]);
    half8 na1 = *reinterpret_cast<const half8*>(&Sk[nb + KCPAD]);
    half8 nb1 = *reinterpret_cast<const half8*>(&Sq[nb + KCPAD]);

    float P[2][6];
#pragma unroll
    for (int rr = 0; rr < 2; ++rr) {
      half8 hk = rr ? a1 : a0;
      half8 hq = rr ? b1 : b0;
      float Dk = 0.f, Ek = 0.f, hks = 0.f, Dq = 0.f, Eq = 0.f, hqs = 0.f;
#pragma unroll
      for (int j = 0; j < 8; ++j) {
        float sk = (float)hk[j], sq = (float)hq[j];
        float tk = __expf(10.f * sk), tq = __expf(10.f * sq);
        float ek = tk * tk, eq = tq * tq;
        hks += tk; hqs += tq;
        Dk += ek * uk[j];
        Dq += eq * uq[j];
        Ek += ek * (wk[j] + uk[j] * (20.f * sk - 10.f * sq));
        Eq += eq * (wq[j] + uq[j] * (20.f * sq - 10.f * sk));
      }
      P[rr][0] = Dk; P[rr][1] = Ek; P[rr][2] = hks;
      P[rr][3] = Dq; P[rr][4] = Eq; P[rr][5] = hqs;
    }
    // 12 independent DPP chains (VALU pipe)
#pragma unroll
    for (int rr = 0; rr < 2; ++rr)
#pragma unroll
      for (int qq = 0; qq < 6; ++qq) P[rr][qq] = dpp_red_sum(P[rr][qq]);
    if (lane == 63) {
#pragma unroll
      for (int rr = 0; rr < 2; ++rr)
#pragma unroll
        for (int qq = 0; qq < 6; ++qq) wred[r + rr][w][qq] = P[rr][qq];
    }
    a0 = na0; b0 = nb0; a1 = na1; b1 = nb1;
  }
  __syncthreads();

  float contrib = 0.f;
  if (t < 32) {
    float v[6] = {0.f, 0.f, 0.f, 0.f, 0.f, 0.f};
#pragma unroll
    for (int ww = 0; ww < 6; ++ww)
#pragma unroll
      for (int qq = 0; qq < 6; ++qq) v[qq] += wred[t][ww][qq];
    contrib = logf(v[5]) - logf(v[0]) + v[1] / v[0]
            + logf(v[2]) - logf(v[3]) + v[4] / v[3];
  }
  if (w == 0) {
#pragma unroll
    for (int o = 32; o; o >>= 1) contrib += __shfl_down(contrib, o, 64);
    if (lane == 0) atomicAdd(accOut, contrib);
  }
}

__global__ void finalize_k(const float* __restrict__ acc, float* __restrict__ out) {
  out[0] = acc[0] * (1.f / 32768.f);  // /(2*B)
}

extern "C" void kernel_launch(void* const* d_in, const int* in_sizes, int n_in,
                              void* d_out, int out_size, void* d_ws, size_t ws_size,
                              hipStream_t stream) {
  const float* q = (const float*)d_in[0];
  const float* k = (const float*)d_in[1];
  const float* c = (const float*)d_in[2];
  float* out = (float*)d_out;

  char* ws = (char*)d_ws;
  float* partK = (float*)ws;                          // 256*3072*4 = 3,145,728 (aliases nk)
  float* partQ = (float*)(ws + 3145728);              // 3,145,728  (aliases nk)
  __bf16* nk = (__bf16*)(ws);                         // 8,388,608 (dead after gemm2)
  __bf16* nc = (__bf16*)(ws + 8388608);               // 1,572,864
  _Float16* Sq = (_Float16*)(ws + 9961472);           // 100,663,296
  _Float16* Sk = (_Float16*)(ws + 110624768);         // 100,663,296
  __bf16* nq = (__bf16*)(ws + 110624768);             // aliases Sk (dead after gemm1)
  float* fb = (float*)(ws + 211288064);
  float* csK0 = fb;             // 3072
  float* csQ0 = fb + 3072;      // 3072
  float* accv = fb + 6144;      // 16
  float* uK0 = fb + 6160;  float* wK0 = fb + 9232;
  float* uK1 = fb + 12304; float* wK1 = fb + 15376;
  float* uK2 = fb + 18448; float* wK2 = fb + 21520;
  float* uQ0 = fb + 24592; float* wQ0 = fb + 27664;
  float* uQ1 = fb + 30736; float* wQ1 = fb + 33808;
  float* uQ2 = fb + 36880; float* wQ2 = fb + 39952;

  hipMemsetAsync(fb, 0, 6160 * sizeof(float), stream);

  normalize_all<<<(2 * BATCH + KCPAD) / 4, 256, 0, stream>>>(q, k, c, nq, nk, nc);

  dim3 gg(BATCH / 128, KCPAD / 128);
  gemm_bf16<<<gg, 256, 0, stream>>>(nq, nc, Sq, csQ0);
  gemm_bf16<<<gg, 256, 0, stream>>>(nk, nc, Sk, csK0);  // overwrites nq (dead)

  reduB<<<24, 256, 0, stream>>>(csK0, csQ0, 1, uK0, wK0, uQ0, wQ0);

  sinkp2<<<2 * NBLK, 384, 0, stream>>>(Sk, Sq, uK0, uQ0, partK, partQ);
  reduB<<<24, 256, 0, stream>>>(partK, partQ, NBLK, uK1, wK1, uQ1, wQ1);
  sinkp2<<<2 * NBLK, 384, 0, stream>>>(Sk, Sq, uK1, uQ1, partK, partQ);
  reduB<<<24, 256, 0, stream>>>(partK, partQ, NBLK, uK2, wK2, uQ2, wQ2);

  kl_kernel<<<512, 384, 0, stream>>>(Sk, Sq, uK2, wK2, uQ2, wQ2, accv);
  finalize_k<<<1, 1, 0, stream>>>(accv, out);
}

// Round 11
// 405.021 us; speedup vs baseline: 1.8589x; 1.8589x over previous
//
#include <hip/hip_runtime.h>

// Problem constants
#define BATCH 16384
#define DIM   256
#define KC    3000
#define KCPAD 3072
#define NBLK  256   // sinkp row-blocks per matrix (64 rows each)

typedef __bf16   bf16x4  __attribute__((ext_vector_type(4)));
typedef __bf16   bf16x8  __attribute__((ext_vector_type(8)));
typedef float    floatx4 __attribute__((ext_vector_type(4)));
typedef _Float16 half8   __attribute__((ext_vector_type(8)));

// async global->LDS, 16B per lane; LDS dest is wave-uniform base + lane*16
#define GLD16(gptr, lptr)                                                              \
  __builtin_amdgcn_global_load_lds((const __attribute__((address_space(1))) void*)(gptr), \
                                   (__attribute__((address_space(3))) void*)(lptr), 16, 0, 0)

// Full wave64 sum via DPP (VALU pipe, no ds_bpermute). Result valid in lane 63.
__device__ __forceinline__ float dpp_red_sum(float x) {
  int xi;
  xi = __builtin_amdgcn_update_dpp(0, __float_as_int(x), 0x111, 0xf, 0xf, true);
  x += __int_as_float(xi);
  xi = __builtin_amdgcn_update_dpp(0, __float_as_int(x), 0x112, 0xf, 0xf, true);
  x += __int_as_float(xi);
  xi = __builtin_amdgcn_update_dpp(0, __float_as_int(x), 0x114, 0xf, 0xf, true);
  x += __int_as_float(xi);
  xi = __builtin_amdgcn_update_dpp(0, __float_as_int(x), 0x118, 0xf, 0xf, true);
  x += __int_as_float(xi);
  xi = __builtin_amdgcn_update_dpp(0, __float_as_int(x), 0x142, 0xa, 0xf, false);
  x += __int_as_float(xi);
  xi = __builtin_amdgcn_update_dpp(0, __float_as_int(x), 0x143, 0xc, 0xf, false);
  x += __int_as_float(xi);
  return x;  // lane 63 = sum of all 64 lanes
}

// ---------------- normalize: one wave per row, float4 in, bf16x4 out ----------------
__global__ __launch_bounds__(256) void normalize_all(const float* __restrict__ q,
                                                     const float* __restrict__ k,
                                                     const float* __restrict__ c,
                                                     __bf16* __restrict__ nq,
                                                     __bf16* __restrict__ nk,
                                                     __bf16* __restrict__ nc) {
  const int wid = threadIdx.x >> 6;
  const int lane = threadIdx.x & 63;
  int row = blockIdx.x * 4 + wid;   // 0 .. 35839
  const float* src;
  __bf16* dst;
  int srow;
  bool live = true;
  if (row < BATCH) {
    src = q; dst = nq; srow = row;
  } else if (row < 2 * BATCH) {
    src = k; dst = nk; srow = row - BATCH;
  } else {
    src = c; dst = nc; srow = row - 2 * BATCH; live = srow < KC;
  }
  float4 v = make_float4(0.f, 0.f, 0.f, 0.f);
  if (live) v = *reinterpret_cast<const float4*>(&src[(size_t)srow * DIM + lane * 4]);
  float ss = v.x * v.x + v.y * v.y + v.z * v.z + v.w * v.w;
  ss = dpp_red_sum(ss);
  ss = __shfl(ss, 63, 64);
  float inv = 1.f / fmaxf(sqrtf(ss), 1e-12f);
  bf16x4 o;
  o[0] = (__bf16)(v.x * inv); o[1] = (__bf16)(v.y * inv);
  o[2] = (__bf16)(v.z * inv); o[3] = (__bf16)(v.w * inv);
  *reinterpret_cast<bf16x4*>(&dst[(size_t)srow * DIM + lane * 4]) = o;  // pad rows get 0
}

// ---------------- GEMM (async LDS staging, XOR-swizzled) + fused colsum0 ----------------
__global__ __launch_bounds__(256) void gemm_bf16(const __bf16* __restrict__ A,
                                                 const __bf16* __restrict__ Bm,
                                                 _Float16* __restrict__ S,
                                                 float* __restrict__ csum0) {
  __shared__ __align__(16) __bf16 As[128 * 32];
  __shared__ __align__(16) __bf16 Bs[128 * 32];
  const int tid = threadIdx.x;
  const int bm = blockIdx.x * 128;
  const int bn = blockIdx.y * 128;
  const int wid = tid >> 6;
  const int lane = tid & 63;
  const int wm = (wid >> 1) * 64;
  const int wn = (wid & 1) * 64;
  const int frow = lane & 15;
  const int fq = lane >> 4;   // 16B-chunk quarter

  int src_off[2];
#pragma unroll
  for (int c = 0; c < 2; ++c) {
    int idx = tid + c * 256;
    int r = idx >> 2;
    int cc = idx & 3;
    int swz = (r & 3) ^ ((r >> 2) & 3);
    src_off[c] = r * DIM + ((cc ^ swz) << 3);
  }
  int a_pos[4], b_pos[4];
#pragma unroll
  for (int i = 0; i < 4; ++i) {
    int rowA = wm + i * 16 + frow;
    int rowB = wn + i * 16 + frow;
    a_pos[i] = rowA * 32 + ((fq ^ ((rowA & 3) ^ ((rowA >> 2) & 3))) << 3);
    b_pos[i] = rowB * 32 + ((fq ^ ((rowB & 3) ^ ((rowB >> 2) & 3))) << 3);
  }

  floatx4 acc[4][4] = {};

  for (int kt = 0; kt < DIM; kt += 32) {
    __syncthreads();
#pragma unroll
    for (int c = 0; c < 2; ++c) {
      int idx = tid + c * 256;
      GLD16(A + (size_t)bm * DIM + kt + src_off[c], &As[idx * 8]);
      GLD16(Bm + (size_t)bn * DIM + kt + src_off[c], &Bs[idx * 8]);
    }
    __syncthreads();
    bf16x8 af[4], bfr[4];
#pragma unroll
    for (int i = 0; i < 4; ++i) af[i] = *reinterpret_cast<const bf16x8*>(&As[a_pos[i]]);
#pragma unroll
    for (int j = 0; j < 4; ++j) bfr[j] = *reinterpret_cast<const bf16x8*>(&Bs[b_pos[j]]);
#pragma unroll
    for (int i = 0; i < 4; ++i)
#pragma unroll
      for (int j = 0; j < 4; ++j)
        acc[i][j] = __builtin_amdgcn_mfma_f32_16x16x32_bf16(af[i], bfr[j], acc[i][j], 0, 0, 0);
  }

  const int rgrp = (lane >> 4) * 4;   // C/D: row = (lane>>4)*4 + reg, col = lane&15
  const int cl = lane & 15;
#pragma unroll
  for (int j = 0; j < 4; ++j) {
    int colb = bn + wn + j * 16 + cl;
    bool valid = colb < KC;
    float csumj = 0.f;
#pragma unroll
    for (int i = 0; i < 4; ++i) {
#pragma unroll
      for (int r = 0; r < 4; ++r) {
        int rowb = bm + wm + i * 16 + rgrp + r;
        float sv = acc[i][j][r];
        S[(size_t)rowb * KCPAD + colb] = (_Float16)(valid ? sv : -3000.0f);
        csumj += __expf(20.f * sv);
      }
    }
    csumj = valid ? csumj : 0.f;
    csumj += __shfl_xor(csumj, 16, 64);
    csumj += __shfl_xor(csumj, 32, 64);
    if (lane < 16 && valid) atomicAdd(&csum0[colb], csumj);
  }
}

// ---------------- column reduce (K and Q): partials -> u = 1/(K*sum), w = u*log(u) ----
__global__ __launch_bounds__(256) void reduB(const float* __restrict__ partK,
                                             const float* __restrict__ partQ, int nparts,
                                             float* __restrict__ uK, float* __restrict__ wK,
                                             float* __restrict__ uQ, float* __restrict__ wQ) {
  int b = blockIdx.x;  // 0..23
  const float* parts;
  float *u, *w;
  if (b < 12) { parts = partK; u = uK; w = wK; }
  else        { parts = partQ; u = uQ; w = wQ; b -= 12; }
  int col = b * 256 + threadIdx.x;
  float s;
  if (nparts == 1) {
    s = parts[col];
  } else {
    float a0 = 0.f, a1 = 0.f, a2 = 0.f, a3 = 0.f;
    for (int i = 0; i < nparts; i += 4) {
      a0 += parts[(size_t)(i + 0) * KCPAD + col];
      a1 += parts[(size_t)(i + 1) * KCPAD + col];
      a2 += parts[(size_t)(i + 2) * KCPAD + col];
      a3 += parts[(size_t)(i + 3) * KCPAD + col];
    }
    s = (a0 + a1) + (a2 + a3);
  }
  if (col >= KC) { u[col] = 0.f; w[col] = 0.f; return; }
  float uu = 1.f / (3000.f * s);
  u[col] = uu;
  w[col] = uu * logf(uu);
}

// ---------------- fused sinkhorn pass (round-7 known-good structure) ----------------
// blocks 0..255 -> Sk rows, 256..511 -> Sq rows; 64 rows/block (4 chunks of 16).
// Single hv[16] buffer, loads at top of each chunk — NO cross-chunk prefetch
// (any structure with >16 half8 loads in flight across the barrier spills: R9/R10).
__global__ __launch_bounds__(384, 2) void sinkp2(const _Float16* __restrict__ Sk,
                                                 const _Float16* __restrict__ Sq,
                                                 const float* __restrict__ uK,
                                                 const float* __restrict__ uQ,
                                                 float* __restrict__ partK,
                                                 float* __restrict__ partQ) {
  __shared__ float wred[16][6];
  __shared__ float vsh[16];
  const int t = threadIdx.x;
  const int w = t >> 6;
  const int lane = t & 63;
  const int col0 = t * 8;

  const _Float16* S;
  const float* uin;
  float* part;
  int rblk = blockIdx.x;
  if (rblk < NBLK) { S = Sk; uin = uK; part = partK; }
  else             { S = Sq; uin = uQ; part = partQ; rblk -= NBLK; }

  float u[8];
  {
    float4 c0 = *reinterpret_cast<const float4*>(&uin[col0]);
    float4 c1 = *reinterpret_cast<const float4*>(&uin[col0 + 4]);
    u[0] = c0.x; u[1] = c0.y; u[2] = c0.z; u[3] = c0.w;
    u[4] = c1.x; u[5] = c1.y; u[6] = c1.z; u[7] = c1.w;
  }

  const int r0 = rblk * 64;
  float creg[8] = {0.f, 0.f, 0.f, 0.f, 0.f, 0.f, 0.f, 0.f};

  for (int ch = 0; ch < 4; ++ch) {
    const int rb = r0 + ch * 16;
    half8 hv[16];
#pragma unroll
    for (int r = 0; r < 16; ++r)
      hv[r] = *reinterpret_cast<const half8*>(&S[(size_t)(rb + r) * KCPAD + col0]);

    float d[16];
#pragma unroll
    for (int r = 0; r < 16; ++r) {
      float dot = 0.f;
#pragma unroll
      for (int j = 0; j < 8; ++j) dot += __expf(20.f * (float)hv[r][j]) * u[j];
      d[r] = dot;
    }
    // 16 independent DPP reduction chains (VALU pipe)
#pragma unroll
    for (int r = 0; r < 16; ++r) d[r] = dpp_red_sum(d[r]);
    if (lane == 63) {
#pragma unroll
      for (int r = 0; r < 16; ++r) wred[r][w] = d[r];
    }
    __syncthreads();
    if (t < 16) {
      float tot = wred[t][0] + wred[t][1] + wred[t][2] + wred[t][3] + wred[t][4] + wred[t][5];
      vsh[t] = 1.f / (16384.f * tot);
    }
    __syncthreads();
#pragma unroll
    for (int r = 0; r < 16; ++r) {
      float v = vsh[r];
#pragma unroll
      for (int j = 0; j < 8; ++j) creg[j] += __expf(20.f * (float)hv[r][j]) * v;
    }
    // no 3rd barrier: next wred write is ordered by the next B1 for readers; vsh
    // readers and wred writers touch different arrays.
  }

  float4* pp = reinterpret_cast<float4*>(&part[(size_t)rblk * KCPAD + col0]);
  pp[0] = make_float4(creg[0], creg[1], creg[2], creg[3]);
  pp[1] = make_float4(creg[4], creg[5], creg[6], creg[7]);
}

// ---------------- fused final-iteration + KL (both losses) ----------------
// 2-row chunks with explicit next-pair prefetch; 12 interleaved DPP chains.
__global__ __launch_bounds__(384, 2) void kl_kernel(
    const _Float16* __restrict__ Sk, const _Float16* __restrict__ Sq,
    const float* __restrict__ uK, const float* __restrict__ wK,
    const float* __restrict__ uQ, const float* __restrict__ wQ,
    float* __restrict__ accOut) {
  __shared__ float wred[32][6][6];  // [row][wave][quantity]
  const int t = threadIdx.x;
  const int w = t >> 6;
  const int lane = t & 63;
  const int col0 = t * 8;

  float uk[8], wk[8], uq[8], wq[8];
  {
    float4 a0 = *reinterpret_cast<const float4*>(&uK[col0]);
    float4 a1 = *reinterpret_cast<const float4*>(&uK[col0 + 4]);
    float4 b0 = *reinterpret_cast<const float4*>(&wK[col0]);
    float4 b1 = *reinterpret_cast<const float4*>(&wK[col0 + 4]);
    float4 c0 = *reinterpret_cast<const float4*>(&uQ[col0]);
    float4 c1 = *reinterpret_cast<const float4*>(&uQ[col0 + 4]);
    float4 e0 = *reinterpret_cast<const float4*>(&wQ[col0]);
    float4 e1 = *reinterpret_cast<const float4*>(&wQ[col0 + 4]);
    uk[0]=a0.x;uk[1]=a0.y;uk[2]=a0.z;uk[3]=a0.w;uk[4]=a1.x;uk[5]=a1.y;uk[6]=a1.z;uk[7]=a1.w;
    wk[0]=b0.x;wk[1]=b0.y;wk[2]=b0.z;wk[3]=b0.w;wk[4]=b1.x;wk[5]=b1.y;wk[6]=b1.z;wk[7]=b1.w;
    uq[0]=c0.x;uq[1]=c0.y;uq[2]=c0.z;uq[3]=c0.w;uq[4]=c1.x;uq[5]=c1.y;uq[6]=c1.z;uq[7]=c1.w;
    wq[0]=e0.x;wq[1]=e0.y;wq[2]=e0.z;wq[3]=e0.w;wq[4]=e1.x;wq[5]=e1.y;wq[6]=e1.z;wq[7]=e1.w;
  }

  const int r0 = blockIdx.x * 32;
  size_t base0 = (size_t)r0 * KCPAD + col0;
  half8 a0 = *reinterpret_cast<const half8*>(&Sk[base0]);
  half8 b0 = *reinterpret_cast<const half8*>(&Sq[base0]);
  half8 a1 = *reinterpret_cast<const half8*>(&Sk[base0 + KCPAD]);
  half8 b1 = *reinterpret_cast<const half8*>(&Sq[base0 + KCPAD]);

#pragma unroll
  for (int r = 0; r < 32; r += 2) {
    const int rn = (r + 2 < 32) ? r + 2 : 0;
    size_t nb = (size_t)(r0 + rn) * KCPAD + col0;
    half8 na0 = *reinterpret_cast<const half8*>(&Sk[nb]);
    half8 nb0 = *reinterpret_cast<const half8*>(&Sq[nb]);
    half8 na1 = *reinterpret_cast<const half8*>(&Sk[nb + KCPAD]);
    half8 nb1 = *reinterpret_cast<const half8*>(&Sq[nb + KCPAD]);

    float P[2][6];
#pragma unroll
    for (int rr = 0; rr < 2; ++rr) {
      half8 hk = rr ? a1 : a0;
      half8 hq = rr ? b1 : b0;
      float Dk = 0.f, Ek = 0.f, hks = 0.f, Dq = 0.f, Eq = 0.f, hqs = 0.f;
#pragma unroll
      for (int j = 0; j < 8; ++j) {
        float sk = (float)hk[j], sq = (float)hq[j];
        float tk = __expf(10.f * sk), tq = __expf(10.f * sq);
        float ek = tk * tk, eq = tq * tq;
        hks += tk; hqs += tq;
        Dk += ek * uk[j];
        Dq += eq * uq[j];
        Ek += ek * (wk[j] + uk[j] * (20.f * sk - 10.f * sq));
        Eq += eq * (wq[j] + uq[j] * (20.f * sq - 10.f * sk));
      }
      P[rr][0] = Dk; P[rr][1] = Ek; P[rr][2] = hks;
      P[rr][3] = Dq; P[rr][4] = Eq; P[rr][5] = hqs;
    }
#pragma unroll
    for (int rr = 0; rr < 2; ++rr)
#pragma unroll
      for (int qq = 0; qq < 6; ++qq) P[rr][qq] = dpp_red_sum(P[rr][qq]);
    if (lane == 63) {
#pragma unroll
      for (int rr = 0; rr < 2; ++rr)
#pragma unroll
        for (int qq = 0; qq < 6; ++qq) wred[r + rr][w][qq] = P[rr][qq];
    }
    a0 = na0; b0 = nb0; a1 = na1; b1 = nb1;
  }
  __syncthreads();

  float contrib = 0.f;
  if (t < 32) {
    float v[6] = {0.f, 0.f, 0.f, 0.f, 0.f, 0.f};
#pragma unroll
    for (int ww = 0; ww < 6; ++ww)
#pragma unroll
      for (int qq = 0; qq < 6; ++qq) v[qq] += wred[t][ww][qq];
    contrib = logf(v[5]) - logf(v[0]) + v[1] / v[0]
            + logf(v[2]) - logf(v[3]) + v[4] / v[3];
  }
  if (w == 0) {
#pragma unroll
    for (int o = 32; o; o >>= 1) contrib += __shfl_down(contrib, o, 64);
    if (lane == 0) atomicAdd(accOut, contrib);
  }
}

__global__ void finalize_k(const float* __restrict__ acc, float* __restrict__ out) {
  out[0] = acc[0] * (1.f / 32768.f);  // /(2*B)
}

extern "C" void kernel_launch(void* const* d_in, const int* in_sizes, int n_in,
                              void* d_out, int out_size, void* d_ws, size_t ws_size,
                              hipStream_t stream) {
  const float* q = (const float*)d_in[0];
  const float* k = (const float*)d_in[1];
  const float* c = (const float*)d_in[2];
  float* out = (float*)d_out;

  char* ws = (char*)d_ws;
  float* partK = (float*)ws;                          // 256*3072*4 = 3,145,728 (aliases nk)
  float* partQ = (float*)(ws + 3145728);              // 3,145,728  (aliases nk)
  __bf16* nk = (__bf16*)(ws);                         // 8,388,608 (dead after gemm2)
  __bf16* nc = (__bf16*)(ws + 8388608);               // 1,572,864
  _Float16* Sq = (_Float16*)(ws + 9961472);           // 100,663,296
  _Float16* Sk = (_Float16*)(ws + 110624768);         // 100,663,296
  __bf16* nq = (__bf16*)(ws + 110624768);             // aliases Sk (dead after gemm1)
  float* fb = (float*)(ws + 211288064);
  float* csK0 = fb;             // 3072
  float* csQ0 = fb + 3072;      // 3072
  float* accv = fb + 6144;      // 16
  float* uK0 = fb + 6160;  float* wK0 = fb + 9232;
  float* uK1 = fb + 12304; float* wK1 = fb + 15376;
  float* uK2 = fb + 18448; float* wK2 = fb + 21520;
  float* uQ0 = fb + 24592; float* wQ0 = fb + 27664;
  float* uQ1 = fb + 30736; float* wQ1 = fb + 33808;
  float* uQ2 = fb + 36880; float* wQ2 = fb + 39952;

  hipMemsetAsync(fb, 0, 6160 * sizeof(float), stream);

  normalize_all<<<(2 * BATCH + KCPAD) / 4, 256, 0, stream>>>(q, k, c, nq, nk, nc);

  dim3 gg(BATCH / 128, KCPAD / 128);
  gemm_bf16<<<gg, 256, 0, stream>>>(nq, nc, Sq, csQ0);
  gemm_bf16<<<gg, 256, 0, stream>>>(nk, nc, Sk, csK0);  // overwrites nq (dead)

  reduB<<<24, 256, 0, stream>>>(csK0, csQ0, 1, uK0, wK0, uQ0, wQ0);

  sinkp2<<<2 * NBLK, 384, 0, stream>>>(Sk, Sq, uK0, uQ0, partK, partQ);
  reduB<<<24, 256, 0, stream>>>(partK, partQ, NBLK, uK1, wK1, uQ1, wQ1);
  sinkp2<<<2 * NBLK, 384, 0, stream>>>(Sk, Sq, uK1, uQ1, partK, partQ);
  reduB<<<24, 256, 0, stream>>>(partK, partQ, NBLK, uK2, wK2, uQ2, wQ2);

  kl_kernel<<<512, 384, 0, stream>>>(Sk, Sq, uK2, wK2, uQ2, wQ2, accv);
  finalize_k<<<1, 1, 0, stream>>>(accv, out);
}